// Round 2
// baseline (165.323 us; speedup 1.0000x reference)
//
#include <hip/hip_runtime.h>

// ---------------------------------------------------------------------------
// CNN + FC + 2x GraphSAGE, collapsed to scalar fields (GNN part is linear).
//   per (n,b): h5 = MLP(x_row);  t1 = g1_wl@h5, t2 = g1_wr@h5
//   sa = g2_wl.t1, sr1 = g2_wr.t1, sc = g2_wl.t2, sr2 = g2_wr.t2
//   u = meanAgg(sa), v = meanAgg(sr1), W = u + sc
//   out = meanAgg(W) + v + kb1*[deg>0] + kb2 + g2_bl
// 5 dispatches: mlp -> agg1(+deg) -> fin1 -> agg2 -> final. No memsets
// (mlp zero-inits the accumulators; deg counted inside agg1).
// ---------------------------------------------------------------------------

__global__ __launch_bounds__(256) void k_mlp(
    const float* __restrict__ x,
    const float* __restrict__ w_t, const float* __restrict__ b_t,
    const float* __restrict__ w_r, const float* __restrict__ b_r,
    const float* __restrict__ w_tp, const float* __restrict__ b_tp,
    const float* __restrict__ w_ssr, const float* __restrict__ b_ssr,
    const float* __restrict__ f1w, const float* __restrict__ f1b,
    const float* __restrict__ f2w, const float* __restrict__ f2b,
    const float* __restrict__ g1_wl, const float* __restrict__ g1_wr,
    const float* __restrict__ g2_wl, const float* __restrict__ g2_wr,
    float* __restrict__ F1, float* __restrict__ F2,
    int* __restrict__ degi, float* __restrict__ A1, float* __restrict__ A2,
    int N, int rows) {
  int rr = blockIdx.x * 256 + threadIdx.x;
  if (rr >= rows) return;

  // ---- load the full 108-float row up front: 27 outstanding float4 loads ----
  const float4* xv = reinterpret_cast<const float4*>(x + (size_t)rr * 108);
  float4 v[27];
#pragma unroll
  for (int i = 0; i < 27; ++i) v[i] = xv[i];

  float feat[32];
#pragma unroll
  for (int i = 0; i < 3; ++i) {
    feat[4 * i + 0] = v[i].x; feat[4 * i + 1] = v[i].y;
    feat[4 * i + 2] = v[i].z; feat[4 * i + 3] = v[i].w;
  }
  const float* cw[4] = {w_t, w_r, w_tp, w_ssr};
  const float* cb[4] = {b_t, b_r, b_tp, b_ssr};
#pragma unroll
  for (int br = 0; br < 4; ++br) {
    float acc[5];
#pragma unroll
    for (int o = 0; o < 5; ++o) acc[o] = cb[br][o];
#pragma unroll
    for (int q = 0; q < 6; ++q) {
      float4 w4 = v[3 + 6 * br + q];
#pragma unroll
      for (int o = 0; o < 5; ++o) {
        acc[o] = fmaf(w4.x, cw[br][o * 24 + 4 * q + 0], acc[o]);
        acc[o] = fmaf(w4.y, cw[br][o * 24 + 4 * q + 1], acc[o]);
        acc[o] = fmaf(w4.z, cw[br][o * 24 + 4 * q + 2], acc[o]);
        acc[o] = fmaf(w4.w, cw[br][o * 24 + 4 * q + 3], acc[o]);
      }
    }
#pragma unroll
    for (int o = 0; o < 5; ++o) feat[12 + br * 5 + o] = fmaxf(acc[o], 0.f);
  }

  float h20[20];
#pragma unroll
  for (int o = 0; o < 20; ++o) {
    float acc = f1b[o];
#pragma unroll
    for (int i = 0; i < 32; ++i) acc = fmaf(feat[i], f1w[o * 32 + i], acc);
    h20[o] = fmaxf(acc, 0.f);
  }
  float h5[5];
#pragma unroll
  for (int o = 0; o < 5; ++o) {
    float acc = f2b[o];
#pragma unroll
    for (int i = 0; i < 20; ++i) acc = fmaf(h20[i], f2w[o * 20 + i], acc);
    h5[o] = acc;
  }

  // ---- fold the two (linear) SAGE layers into 4 scalars ----
  float sa = 0.f, sr1 = 0.f, sc = 0.f, sr2 = 0.f;
#pragma unroll
  for (int j = 0; j < 20; ++j) {
    float t1 = 0.f, t2 = 0.f;
#pragma unroll
    for (int k = 0; k < 5; ++k) {
      t1 = fmaf(g1_wl[j * 5 + k], h5[k], t1);
      t2 = fmaf(g1_wr[j * 5 + k], h5[k], t2);
    }
    float wl2 = g2_wl[j], wr2 = g2_wr[j];
    sa  = fmaf(wl2, t1, sa);
    sr1 = fmaf(wr2, t1, sr1);
    sc  = fmaf(wl2, t2, sc);
    sr2 = fmaf(wr2, t2, sr2);
  }

  int b = rr / N;
  int n = rr - b * N;
  reinterpret_cast<float2*>(F1)[n * 16 + b] = make_float2(sa, sr1);
  reinterpret_cast<float2*>(F2)[n * 16 + b] = make_float2(sc, sr2);
  // zero-init accumulators for the aggregation passes (replaces memsets)
  reinterpret_cast<float2*>(A1)[n * 16 + b] = make_float2(0.f, 0.f);
  A2[n * 16 + b] = 0.f;
  if (b == 0) degi[n] = 0;
}

// one (edge, batch) pair per thread: float2 gather + 2 atomics; lane b==0 counts deg
__global__ void k_agg1(const int* __restrict__ src, const int* __restrict__ dst, int E,
                       const float* __restrict__ F1, float* __restrict__ A1,
                       int* __restrict__ degi) {
  int t = blockIdx.x * blockDim.x + threadIdx.x;
  int e = t >> 4, b = t & 15;
  if (e >= E) return;
  int s = src[e], d = dst[e];
  float2 f = reinterpret_cast<const float2*>(F1)[s * 16 + b];
  atomicAdd(&A1[d * 32 + 2 * b + 0], f.x);
  atomicAdd(&A1[d * 32 + 2 * b + 1], f.y);
  if (b == 0) atomicAdd(&degi[d], 1);
}

// W[n*16+b] = mean(sa) + sc
__global__ void k_fin1(const float* __restrict__ A1, const float* __restrict__ F2,
                       const int* __restrict__ degi, float* __restrict__ W, int N) {
  int t = blockIdx.x * blockDim.x + threadIdx.x;
  if (t < N * 16) {
    int n = t >> 4, b = t & 15;
    float inv = 1.0f / fmaxf((float)degi[n], 1.0f);
    W[t] = A1[n * 32 + 2 * b] * inv + F2[n * 32 + 2 * b];
  }
}

__global__ void k_agg2(const int* __restrict__ src, const int* __restrict__ dst, int E,
                       const float* __restrict__ W, float* __restrict__ A2) {
  int t = blockIdx.x * blockDim.x + threadIdx.x;
  int e = t >> 4, b = t & 15;
  if (e >= E) return;
  int s = src[e], d = dst[e];
  atomicAdd(&A2[d * 16 + b], W[s * 16 + b]);
}

__global__ void k_final(const float* __restrict__ A1, const float* __restrict__ F2,
                        const float* __restrict__ A2, const int* __restrict__ degi,
                        const float* __restrict__ g1_bl, const float* __restrict__ g2_wl,
                        const float* __restrict__ g2_wr, const float* __restrict__ g2_bl,
                        float* __restrict__ out, int N) {
  int t = blockIdx.x * blockDim.x + threadIdx.x;
  if (t < 16 * N) {
    int b = t / N, n = t - b * N;
    float kb1 = 0.f, kb2 = 0.f;
#pragma unroll
    for (int j = 0; j < 20; ++j) {
      kb1 = fmaf(g2_wl[j], g1_bl[j], kb1);
      kb2 = fmaf(g2_wr[j], g1_bl[j], kb2);
    }
    float inv = 1.0f / fmaxf((float)degi[n], 1.0f);
    float chi = degi[n] > 0 ? 1.f : 0.f;
    out[t] = (A2[n * 16 + b] + A1[n * 32 + 2 * b + 1]) * inv
             + F2[n * 32 + 2 * b + 1] + kb1 * chi + kb2 + g2_bl[0];
  }
}

extern "C" void kernel_launch(void* const* d_in, const int* in_sizes, int n_in,
                              void* d_out, int out_size, void* d_ws, size_t ws_size,
                              hipStream_t stream) {
  const float* x     = (const float*)d_in[0];
  const int*   ei    = (const int*)d_in[1];
  const float* w_t   = (const float*)d_in[2];
  const float* b_t   = (const float*)d_in[3];
  const float* w_r   = (const float*)d_in[4];
  const float* b_r   = (const float*)d_in[5];
  const float* w_tp  = (const float*)d_in[6];
  const float* b_tp  = (const float*)d_in[7];
  const float* w_ssr = (const float*)d_in[8];
  const float* b_ssr = (const float*)d_in[9];
  const float* f1w   = (const float*)d_in[10];
  const float* f1b   = (const float*)d_in[11];
  const float* f2w   = (const float*)d_in[12];
  const float* f2b   = (const float*)d_in[13];
  const float* g1_wl = (const float*)d_in[14];
  const float* g1_bl = (const float*)d_in[15];
  const float* g1_wr = (const float*)d_in[16];
  const float* g2_wl = (const float*)d_in[17];
  const float* g2_bl = (const float*)d_in[18];
  const float* g2_wr = (const float*)d_in[19];
  float* out = (float*)d_out;

  const int E = in_sizes[1] / 2;
  const int N = out_size / 16;   // B = 16
  const int rows = out_size;     // N * B
  const int* src = ei;
  const int* dst = ei + E;

  // workspace layout (floats)
  float* ws = (float*)d_ws;
  float* F1 = ws;                      // 32*N  [n][b]{sa,sr1}
  float* F2 = F1 + (size_t)32 * N;     // 32*N  [n][b]{sc,sr2}
  float* A1 = F2 + (size_t)32 * N;     // 32*N
  float* A2 = A1 + (size_t)32 * N;     // 16*N
  float* W  = A2 + (size_t)16 * N;     // 16*N
  int* degi = (int*)(W + (size_t)16 * N);  // N

  k_mlp<<<(rows + 255) / 256, 256, 0, stream>>>(
      x, w_t, b_t, w_r, b_r, w_tp, b_tp, w_ssr, b_ssr,
      f1w, f1b, f2w, f2b, g1_wl, g1_wr, g2_wl, g2_wr,
      F1, F2, degi, A1, A2, N, rows);

  int tE = ((E * 16) + 255) / 256;
  k_agg1<<<tE, 256, 0, stream>>>(src, dst, E, F1, A1, degi);
  k_fin1<<<(N * 16 + 255) / 256, 256, 0, stream>>>(A1, F2, degi, W, N);
  k_agg2<<<tE, 256, 0, stream>>>(src, dst, E, W, A2);
  k_final<<<(N * 16 + 255) / 256, 256, 0, stream>>>(
      A1, F2, A2, degi, g1_bl, g2_wl, g2_wr, g2_bl, out, N);
}